// Round 1
// baseline (3424.762 us; speedup 1.0000x reference)
//
#include <hip/hip_runtime.h>

#define BB 4
#define SS 8192
#define DD 1024
#define HH 16
#define DKK 64
#define EPSV 1e-6f
// M_TOTAL = BB*SS = 32768

// ---------------------------------------------------------------------------
// Generic NT GEMM:  out = act(A[M,K] @ W[N,K]^T + bias)
// M=32768, N=1024, K=1024. BM=BN=128, BK=16, 256 threads, 8x8 microtile.
// HEAD_LAYOUT: store to [B,H,S,DK] (projections). else [M,N] row-major.
// RELU_EPS: apply relu(x)+EPS (q,k projections).
// ---------------------------------------------------------------------------
template<bool RELU_EPS, bool HEAD_LAYOUT>
__global__ __launch_bounds__(256)
void gemm_nt(const float* __restrict__ Amat, const float* __restrict__ W,
             const float* __restrict__ bias, float* __restrict__ out) {
    constexpr int BM = 128, BN = 128, BK = 16, K = 1024;
    __shared__ float As[BK][BM + 4];   // row stride 132 floats: 16B-aligned rows
    __shared__ float Bs[BK][BN + 4];
    const int tid = threadIdx.x;
    const int tx = tid & 15, ty = tid >> 4;
    const int m0 = blockIdx.x * BM, n0 = blockIdx.y * BN;

    float acc[8][8];
    #pragma unroll
    for (int i = 0; i < 8; ++i)
        #pragma unroll
        for (int j = 0; j < 8; ++j) acc[i][j] = 0.f;

    for (int k0 = 0; k0 < K; k0 += BK) {
        // stage A,B tiles (transposed into LDS: [k][m] / [k][n])
        #pragma unroll
        for (int l = 0; l < 2; ++l) {
            int f = tid + l * 256;            // 0..511
            int r = f >> 2, c4 = (f & 3) << 2;
            float4 av = *(const float4*)&Amat[(size_t)(m0 + r) * K + k0 + c4];
            As[c4 + 0][r] = av.x; As[c4 + 1][r] = av.y;
            As[c4 + 2][r] = av.z; As[c4 + 3][r] = av.w;
            float4 bv = *(const float4*)&W[(size_t)(n0 + r) * K + k0 + c4];
            Bs[c4 + 0][r] = bv.x; Bs[c4 + 1][r] = bv.y;
            Bs[c4 + 2][r] = bv.z; Bs[c4 + 3][r] = bv.w;
        }
        __syncthreads();
        #pragma unroll
        for (int kk = 0; kk < BK; ++kk) {
            float a[8], b[8];
            *(float4*)&a[0] = *(const float4*)&As[kk][ty * 8];
            *(float4*)&a[4] = *(const float4*)&As[kk][ty * 8 + 4];
            // cols split in two 64-wide groups -> 2-way LDS aliasing (free)
            *(float4*)&b[0] = *(const float4*)&Bs[kk][tx * 4];
            *(float4*)&b[4] = *(const float4*)&Bs[kk][64 + tx * 4];
            #pragma unroll
            for (int i = 0; i < 8; ++i)
                #pragma unroll
                for (int j = 0; j < 8; ++j)
                    acc[i][j] = fmaf(a[i], b[j], acc[i][j]);
        }
        __syncthreads();
    }

    float bvec[8];
    *(float4*)&bvec[0] = *(const float4*)&bias[n0 + tx * 4];
    *(float4*)&bvec[4] = *(const float4*)&bias[n0 + 64 + tx * 4];

    #pragma unroll
    for (int i = 0; i < 8; ++i) {
        int m = m0 + ty * 8 + i;
        int bb = m >> 13, s = m & (SS - 1);
        #pragma unroll
        for (int jg = 0; jg < 2; ++jg) {
            int n = n0 + jg * 64 + tx * 4;
            float4 o;
            o.x = acc[i][jg * 4 + 0] + bvec[jg * 4 + 0];
            o.y = acc[i][jg * 4 + 1] + bvec[jg * 4 + 1];
            o.z = acc[i][jg * 4 + 2] + bvec[jg * 4 + 2];
            o.w = acc[i][jg * 4 + 3] + bvec[jg * 4 + 3];
            if (RELU_EPS) {
                o.x = fmaxf(o.x, 0.f) + EPSV;
                o.y = fmaxf(o.y, 0.f) + EPSV;
                o.z = fmaxf(o.z, 0.f) + EPSV;
                o.w = fmaxf(o.w, 0.f) + EPSV;
            }
            if (HEAD_LAYOUT) {
                int h = n >> 6, d = n & 63;
                *(float4*)&out[(((size_t)bb * HH + h) * SS + s) * DKK + d] = o;
            } else {
                *(float4*)&out[(size_t)m * DD + n] = o;
            }
        }
    }
}

// ---------------------------------------------------------------------------
// kv[bh][d][e] = sum_s k[bh][s][d]*v[bh][s][e];  ksum[bh][d] = sum_s k[bh][s][d]
// grid (16 s-chunks of 512, 64 bh). Partial sums accumulated via atomics.
// ---------------------------------------------------------------------------
__global__ __launch_bounds__(256)
void kv_ksum_kernel(const float* __restrict__ k, const float* __restrict__ v,
                    float* __restrict__ kv, float* __restrict__ ksum) {
    __shared__ float kt[64][64];
    __shared__ float vt[64][64];
    const int bh = blockIdx.y;
    const int tid = threadIdx.x;
    const int d0 = (tid >> 4) << 2;
    const int e0 = (tid & 15) << 2;
    float acc[4][4];
    #pragma unroll
    for (int i = 0; i < 4; ++i)
        #pragma unroll
        for (int j = 0; j < 4; ++j) acc[i][j] = 0.f;
    float ksl = 0.f;

    const size_t base = ((size_t)bh * SS + (size_t)blockIdx.x * 512) * DKK;
    for (int sub = 0; sub < 8; ++sub) {
        #pragma unroll
        for (int l = 0; l < 4; ++l) {
            int f = tid + l * 256;          // 0..1023
            int r = f >> 4, c = (f & 15) << 2;
            *(float4*)&kt[r][c] = *(const float4*)&k[base + sub * 4096 + (size_t)r * 64 + c];
            *(float4*)&vt[r][c] = *(const float4*)&v[base + sub * 4096 + (size_t)r * 64 + c];
        }
        __syncthreads();
        for (int ss = 0; ss < 64; ++ss) {
            float4 ka = *(const float4*)&kt[ss][d0];
            float4 va = *(const float4*)&vt[ss][e0];
            float ar[4] = {ka.x, ka.y, ka.z, ka.w};
            float vr[4] = {va.x, va.y, va.z, va.w};
            #pragma unroll
            for (int i = 0; i < 4; ++i)
                #pragma unroll
                for (int j = 0; j < 4; ++j)
                    acc[i][j] = fmaf(ar[i], vr[j], acc[i][j]);
        }
        if (tid < 64) {
            for (int ss = 0; ss < 64; ++ss) ksl += kt[ss][tid];
        }
        __syncthreads();
    }
    float* kvb = kv + (size_t)bh * 4096;
    #pragma unroll
    for (int i = 0; i < 4; ++i)
        #pragma unroll
        for (int j = 0; j < 4; ++j)
            atomicAdd(&kvb[(d0 + i) * 64 + (e0 + j)], acc[i][j]);
    if (tid < 64) atomicAdd(&ksum[bh * 64 + tid], ksl);
}

// ---------------------------------------------------------------------------
// mid[b][s][h*64+e] = (sum_d q[bh][s][d]*kv[bh][d][e]) / (sum_d q*ksum + EPS)
// grid (32 s-chunks of 256, 64 bh). kv column cached in 64 VGPRs per lane.
// ---------------------------------------------------------------------------
__global__ __launch_bounds__(256)
void qkv_norm_kernel(const float* __restrict__ q, const float* __restrict__ kv,
                     const float* __restrict__ ksum, float* __restrict__ mid) {
    __shared__ float kvs[64][65];
    __shared__ float ks[64];
    __shared__ float qrow[4][64];
    const int bh = blockIdx.y, b = bh >> 4, h = bh & 15;
    const int tid = threadIdx.x;
    for (int i = tid; i < 4096; i += 256) kvs[i >> 6][i & 63] = kv[(size_t)bh * 4096 + i];
    if (tid < 64) ks[tid] = ksum[bh * 64 + tid];
    __syncthreads();
    const int g = tid >> 6, lane = tid & 63;
    float kvc[64];
    #pragma unroll
    for (int d = 0; d < 64; ++d) kvc[d] = kvs[d][lane];   // (d+lane)%32 banks: free
    const float ksl = ks[lane];
    const size_t qbase = (size_t)bh * SS * DKK;
    const int s0 = blockIdx.x * 256;
    for (int it = 0; it < 64; ++it) {
        int s = s0 + (it << 2) + g;
        float qv = q[qbase + (size_t)s * DKK + lane];
        qrow[g][lane] = qv;          // wave-private row buffer (one wave per g)
        float qks = qv * ksl;
        #pragma unroll
        for (int off = 32; off >= 1; off >>= 1) qks += __shfl_xor(qks, off, 64);
        float o = 0.f;
        #pragma unroll
        for (int d4 = 0; d4 < 64; d4 += 4) {
            float4 qq = *(const float4*)&qrow[g][d4];   // broadcast read
            o = fmaf(qq.x, kvc[d4 + 0], o);
            o = fmaf(qq.y, kvc[d4 + 1], o);
            o = fmaf(qq.z, kvc[d4 + 2], o);
            o = fmaf(qq.w, kvc[d4 + 3], o);
        }
        mid[((size_t)b * SS + s) * DD + h * DKK + lane] = o / (qks + EPSV);
    }
}

// ---------------------------------------------------------------------------
extern "C" void kernel_launch(void* const* d_in, const int* in_sizes, int n_in,
                              void* d_out, int out_size, void* d_ws, size_t ws_size,
                              hipStream_t stream) {
    const float* x  = (const float*)d_in[0];
    const float* Wq = (const float*)d_in[1];
    const float* bq = (const float*)d_in[2];
    const float* Wk = (const float*)d_in[3];
    const float* bk = (const float*)d_in[4];
    const float* Wv = (const float*)d_in[5];
    const float* bv = (const float*)d_in[6];
    const float* Wo = (const float*)d_in[7];
    const float* bo = (const float*)d_in[8];
    float* outp = (float*)d_out;

    float* ws      = (float*)d_ws;
    float* k_ws    = ws;                    // 33,554,432 floats  [B,H,S,DK]
    float* v_ws    = ws + 33554432;         // 33,554,432 floats  [B,H,S,DK]
    float* kv_ws   = ws + 67108864;         // 262,144 floats     [BH,64,64]
    float* ksum_ws = kv_ws + 262144;        // 4,096 floats       [BH,64]
    float* mid_ws  = k_ws;                  // reuse: k dead after kv_ksum

    dim3 gg(256, 8), gb(256);
    // q -> d_out (reused as scratch; overwritten by final GEMM)
    gemm_nt<true,  true ><<<gg, gb, 0, stream>>>(x, Wq, bq, outp);
    gemm_nt<true,  true ><<<gg, gb, 0, stream>>>(x, Wk, bk, k_ws);
    gemm_nt<false, true ><<<gg, gb, 0, stream>>>(x, Wv, bv, v_ws);

    hipMemsetAsync(kv_ws, 0, (262144 + 4096) * sizeof(float), stream);
    kv_ksum_kernel<<<dim3(16, 64), 256, 0, stream>>>(k_ws, v_ws, kv_ws, ksum_ws);
    qkv_norm_kernel<<<dim3(32, 64), 256, 0, stream>>>(outp, kv_ws, ksum_ws, mid_ws);

    gemm_nt<false, false><<<gg, gb, 0, stream>>>(mid_ws, Wo, bo, outp);
}

// Round 2
// 1468.244 us; speedup vs baseline: 2.3326x; 2.3326x over previous
//
#include <hip/hip_runtime.h>
#include <hip/hip_bf16.h>

#define BB 4
#define SS 8192
#define DD 1024
#define HH 16
#define DKK 64
#define EPSV 1e-6f
// M_TOTAL = 32768, logical K' = 3072 (hi*hi | lo*hi | hi*lo)

typedef unsigned short u16;
typedef __attribute__((ext_vector_type(8))) short bf16x8v;
typedef __attribute__((ext_vector_type(4))) float f32x4v;

__device__ inline u16 f2bf(float f) {
    __hip_bfloat16 b = __float2bfloat16(f);   // RNE
    return *reinterpret_cast<u16*>(&b);
}
__device__ inline float bf2f(u16 u) {
    union { unsigned int i; float f; } c; c.i = ((unsigned int)u) << 16; return c.f;
}

__device__ inline void gload_lds16(const void* g, void* l) {
    __builtin_amdgcn_global_load_lds(
        (const __attribute__((address_space(1))) void*)g,
        (__attribute__((address_space(3))) void*)l, 16, 0, 0);
}

// ---------------------------------------------------------------------------
// split fp32 [R][1024] -> bf16 [R][2048]: cols 0:1024 = hi, 1024:2048 = lo
// ---------------------------------------------------------------------------
__global__ __launch_bounds__(256)
void split_hilo(const float* __restrict__ in, u16* __restrict__ outp, int n4) {
    int i = blockIdx.x * 256 + threadIdx.x;
    if (i >= n4) return;
    size_t e = (size_t)i * 4;
    size_t row = e >> 10; int col = (int)(e & 1023);
    float4 v = *(const float4*)&in[e];
    ushort4 hi, lo;
    hi.x = f2bf(v.x); lo.x = f2bf(v.x - bf2f(hi.x));
    hi.y = f2bf(v.y); lo.y = f2bf(v.y - bf2f(hi.y));
    hi.z = f2bf(v.z); lo.z = f2bf(v.z - bf2f(hi.z));
    hi.w = f2bf(v.w); lo.w = f2bf(v.w - bf2f(hi.w));
    size_t ob = row * 2048 + col;
    *(ushort4*)&outp[ob] = hi;
    *(ushort4*)&outp[ob + 1024] = lo;
}

// ---------------------------------------------------------------------------
// bf16-split NT GEMM: C[m][n] = sum_{k'} A'[m][k'] W'[n][k'] (+bias, act)
// A phys [M][2048] (hi|lo), W phys [1024][2048] (hi|lo). Logical K'=3072:
//   b0: A hi (k),      W hi (k)
//   b1: A lo (k-1024), W hi (k-1024... phys k-1024 -> hi? see maps below)
//   b2: A hi,          W lo
// A phys offset: k0<2048 ? k0 : k0-2048   ([hi, lo, hi])
// W phys offset: k0<1024 ? k0 : k0-1024   ([hi, hi, lo])
// EPI: 0=q fp32 head relu+eps, 1=k bf16 head relu+eps, 2=v bf16 head, 3=fp32 rowmajor
// ---------------------------------------------------------------------------
template<int EPI>
__global__ __launch_bounds__(256)
void gemm_split(const u16* __restrict__ A, const u16* __restrict__ Wsp,
                const float* __restrict__ bias, void* __restrict__ out) {
    __shared__ u16 ldsA[8192];   // 128 rows x 64 cols bf16, XOR-swizzled content
    __shared__ u16 ldsB[8192];

    // XCD-chunked swizzle: 2048 blocks, bid%8 = XCD; each XCD gets 32 m-blocks x 8 n
    int bid  = blockIdx.x;
    int tile = (bid & 7) * 256 + (bid >> 3);
    int m0 = (tile >> 3) * 128;
    int n0 = (tile & 7) * 128;

    const int tid = threadIdx.x;
    const int w = tid >> 6, l = tid & 63;
    const int wm = (w >> 1) * 64, wn = (w & 1) * 64;

    f32x4v acc[4][4];
    #pragma unroll
    for (int i = 0; i < 4; ++i)
        #pragma unroll
        for (int j = 0; j < 4; ++j) acc[i][j] = (f32x4v)0.f;

    const u16* Abase = A   + (size_t)m0 * 2048;
    const u16* Bbase = Wsp + (size_t)n0 * 2048;
    // per-lane source pieces for staging
    const int srow_in_chunk = l >> 3;                       // 0..7
    const int scb = (((l & 7) ^ (l >> 3)) << 4) >> 1;       // swizzled col, ELEMENTS

    for (int k0 = 0; k0 < 3072; k0 += 64) {
        const int ka0 = (k0 < 2048) ? k0 : k0 - 2048;
        const int kw0 = (k0 < 1024) ? k0 : k0 - 1024;
        __syncthreads();
        #pragma unroll
        for (int i = 0; i < 4; ++i) {
            int c = w * 4 + i;                               // chunk 0..15 (wave-uniform)
            int row = c * 8 + srow_in_chunk;
            gload_lds16(Abase + (size_t)row * 2048 + ka0 + scb, &ldsA[c * 512]);
            gload_lds16(Bbase + (size_t)row * 2048 + kw0 + scb, &ldsB[c * 512]);
        }
        __syncthreads();
        #pragma unroll
        for (int ks = 0; ks < 2; ++ks) {
            bf16x8v aF[4], bF[4];
            const int clb = ks * 64 + ((l >> 4) << 4);       // logical col byte
            #pragma unroll
            for (int f = 0; f < 4; ++f) {
                int ra = wm + f * 16 + (l & 15);
                aF[f] = *(const bf16x8v*)((const char*)ldsA + ra * 128 + (clb ^ ((ra & 7) << 4)));
                int rb = wn + f * 16 + (l & 15);
                bF[f] = *(const bf16x8v*)((const char*)ldsB + rb * 128 + (clb ^ ((rb & 7) << 4)));
            }
            #pragma unroll
            for (int fm = 0; fm < 4; ++fm)
                #pragma unroll
                for (int fn = 0; fn < 4; ++fn)
                    acc[fm][fn] = __builtin_amdgcn_mfma_f32_16x16x32_bf16(
                        aF[fm], bF[fn], acc[fm][fn], 0, 0, 0);
        }
    }

    float bv[4];
    #pragma unroll
    for (int fn = 0; fn < 4; ++fn) bv[fn] = bias[n0 + wn + fn * 16 + (l & 15)];

    #pragma unroll
    for (int fm = 0; fm < 4; ++fm)
        #pragma unroll
        for (int fn = 0; fn < 4; ++fn)
            #pragma unroll
            for (int r = 0; r < 4; ++r) {
                int m = m0 + wm + fm * 16 + ((l >> 4) << 2) + r;
                int n = n0 + wn + fn * 16 + (l & 15);
                float o = acc[fm][fn][r] + bv[fn];
                if (EPI == 0 || EPI == 1) o = fmaxf(o, 0.f) + EPSV;
                if (EPI <= 2) {
                    int b = m >> 13, s = m & (SS - 1), h = n >> 6, d = n & 63;
                    size_t idx = (((size_t)b * HH + h) * SS + s) * DKK + d;
                    if (EPI == 0) ((float*)out)[idx] = o;
                    else          ((u16*)out)[idx]   = f2bf(o);
                } else {
                    ((float*)out)[(size_t)m * DD + n] = o;
                }
            }
}

// ---------------------------------------------------------------------------
// kv[bh][d][e] = sum_s k[bh][s][d]*v[bh][s][e]; ksum[bh][d] = sum_s k[bh][s][d]
// k,v are bf16 head-layout. Partials via atomics (kv memset to 0 first).
// ---------------------------------------------------------------------------
__global__ __launch_bounds__(256)
void kv_ksum_kernel(const u16* __restrict__ k, const u16* __restrict__ v,
                    float* __restrict__ kv, float* __restrict__ ksum) {
    __shared__ float kt[64][64];
    __shared__ float vt[64][64];
    const int bh = blockIdx.y;
    const int tid = threadIdx.x;
    const int d0 = (tid >> 4) << 2;
    const int e0 = (tid & 15) << 2;
    float acc[4][4];
    #pragma unroll
    for (int i = 0; i < 4; ++i)
        #pragma unroll
        for (int j = 0; j < 4; ++j) acc[i][j] = 0.f;
    float ksl = 0.f;

    const size_t base = ((size_t)bh * SS + (size_t)blockIdx.x * 512) * DKK;
    for (int sub = 0; sub < 8; ++sub) {
        #pragma unroll
        for (int it = 0; it < 4; ++it) {
            int f = tid + it * 256;
            int r = f >> 4, c = (f & 15) << 2;
            ushort4 ku = *(const ushort4*)&k[base + sub * 4096 + (size_t)r * 64 + c];
            ushort4 vu = *(const ushort4*)&v[base + sub * 4096 + (size_t)r * 64 + c];
            *(float4*)&kt[r][c] = make_float4(bf2f(ku.x), bf2f(ku.y), bf2f(ku.z), bf2f(ku.w));
            *(float4*)&vt[r][c] = make_float4(bf2f(vu.x), bf2f(vu.y), bf2f(vu.z), bf2f(vu.w));
        }
        __syncthreads();
        for (int ss = 0; ss < 64; ++ss) {
            float4 ka = *(const float4*)&kt[ss][d0];
            float4 va = *(const float4*)&vt[ss][e0];
            float ar[4] = {ka.x, ka.y, ka.z, ka.w};
            float vr[4] = {va.x, va.y, va.z, va.w};
            #pragma unroll
            for (int i = 0; i < 4; ++i)
                #pragma unroll
                for (int j = 0; j < 4; ++j)
                    acc[i][j] = fmaf(ar[i], vr[j], acc[i][j]);
        }
        if (tid < 64) {
            for (int ss = 0; ss < 64; ++ss) ksl += kt[ss][tid];
        }
        __syncthreads();
    }
    float* kvb = kv + (size_t)bh * 4096;
    #pragma unroll
    for (int i = 0; i < 4; ++i)
        #pragma unroll
        for (int j = 0; j < 4; ++j)
            atomicAdd(&kvb[(d0 + i) * 64 + (e0 + j)], acc[i][j]);
    if (tid < 64) atomicAdd(&ksum[bh * 64 + tid], ksl);
}

// ---------------------------------------------------------------------------
// mid[m][:] = (q·kv)/(q·ksum+EPS) written SPLIT bf16: [m][h*64+e] hi, +1024 lo
// ---------------------------------------------------------------------------
__global__ __launch_bounds__(256)
void qkv_norm_kernel(const float* __restrict__ q, const float* __restrict__ kv,
                     const float* __restrict__ ksum, u16* __restrict__ mid) {
    __shared__ float kvs[64][65];
    __shared__ float ks[64];
    __shared__ float qrow[4][64];
    const int bh = blockIdx.y, b = bh >> 4, h = bh & 15;
    const int tid = threadIdx.x;
    for (int i = tid; i < 4096; i += 256) kvs[i >> 6][i & 63] = kv[(size_t)bh * 4096 + i];
    if (tid < 64) ks[tid] = ksum[bh * 64 + tid];
    __syncthreads();
    const int g = tid >> 6, lane = tid & 63;
    float kvc[64];
    #pragma unroll
    for (int d = 0; d < 64; ++d) kvc[d] = kvs[d][lane];
    const float ksl = ks[lane];
    const size_t qbase = (size_t)bh * SS * DKK;
    const int s0 = blockIdx.x * 256;
    for (int it = 0; it < 64; ++it) {
        int s = s0 + (it << 2) + g;
        float qv = q[qbase + (size_t)s * DKK + lane];
        qrow[g][lane] = qv;
        float qks = qv * ksl;
        #pragma unroll
        for (int off = 32; off >= 1; off >>= 1) qks += __shfl_xor(qks, off, 64);
        float o = 0.f;
        #pragma unroll
        for (int d4 = 0; d4 < 64; d4 += 4) {
            float4 qq = *(const float4*)&qrow[g][d4];
            o = fmaf(qq.x, kvc[d4 + 0], o);
            o = fmaf(qq.y, kvc[d4 + 1], o);
            o = fmaf(qq.z, kvc[d4 + 2], o);
            o = fmaf(qq.w, kvc[d4 + 3], o);
        }
        o = o / (qks + EPSV);
        u16 hi = f2bf(o);
        u16 lo = f2bf(o - bf2f(hi));
        size_t ob = ((size_t)b * SS + s) * 2048 + h * DKK + lane;
        mid[ob] = hi;
        mid[ob + 1024] = lo;
    }
}

// ---------------------------------------------------------------------------
extern "C" void kernel_launch(void* const* d_in, const int* in_sizes, int n_in,
                              void* d_out, int out_size, void* d_ws, size_t ws_size,
                              hipStream_t stream) {
    const float* x  = (const float*)d_in[0];
    const float* Wq = (const float*)d_in[1];
    const float* bq = (const float*)d_in[2];
    const float* Wk = (const float*)d_in[3];
    const float* bk = (const float*)d_in[4];
    const float* Wv = (const float*)d_in[5];
    const float* bv = (const float*)d_in[6];
    const float* Wo = (const float*)d_in[7];
    const float* bo = (const float*)d_in[8];

    char* ws = (char*)d_ws;
    u16*   xsplit  = (u16*)ws;                          // 134,217,728 B
    u16*   wsplit  = (u16*)(ws + 134217728);            //   4,194,304 B
    u16*   k_ws    = (u16*)(ws + 138412032);            //  67,108,864 B
    u16*   v_ws    = (u16*)(ws + 205520896);            //  67,108,864 B
    float* kv_ws   = (float*)(ws + 272629760);          //   1,048,576 B
    float* ksum_ws = (float*)(ws + 273678336);          //      16,384 B
    u16*   midsplit = xsplit;                           // overlays xsplit (dead)
    float* q_ws    = (float*)d_out;                     // q in d_out (fp32 head)

    // split x once; W per-GEMM into the shared wsplit buffer
    split_hilo<<<32768, 256, 0, stream>>>(x, xsplit, 8388608);

    split_hilo<<<1024, 256, 0, stream>>>(Wq, wsplit, 262144);
    gemm_split<0><<<2048, 256, 0, stream>>>(xsplit, wsplit, bq, (void*)q_ws);
    split_hilo<<<1024, 256, 0, stream>>>(Wk, wsplit, 262144);
    gemm_split<1><<<2048, 256, 0, stream>>>(xsplit, wsplit, bk, (void*)k_ws);
    split_hilo<<<1024, 256, 0, stream>>>(Wv, wsplit, 262144);
    gemm_split<2><<<2048, 256, 0, stream>>>(xsplit, wsplit, bv, (void*)v_ws);

    hipMemsetAsync(kv_ws, 0, 1048576 + 16384, stream);
    kv_ksum_kernel<<<dim3(16, 64), 256, 0, stream>>>(k_ws, v_ws, kv_ws, ksum_ws);
    qkv_norm_kernel<<<dim3(32, 64), 256, 0, stream>>>(q_ws, kv_ws, ksum_ws, midsplit);

    split_hilo<<<1024, 256, 0, stream>>>(Wo, wsplit, 262144);
    gemm_split<3><<<2048, 256, 0, stream>>>(midsplit, wsplit, bo, d_out);
}

// Round 3
// 1179.830 us; speedup vs baseline: 2.9028x; 1.2445x over previous
//
#include <hip/hip_runtime.h>
#include <hip/hip_bf16.h>

#define BB 4
#define SS 8192
#define DD 1024
#define HH 16
#define DKK 64
#define EPSV 1e-6f
// M_TOTAL = 32768, logical K' = 3072 (hi*hi | lo*hi | hi*lo), NT = 48 K-tiles of 64

typedef unsigned short u16;
typedef __attribute__((ext_vector_type(8))) short bf16x8v;
typedef __attribute__((ext_vector_type(4))) float f32x4v;

__device__ inline u16 f2bf(float f) {
    __hip_bfloat16 b = __float2bfloat16(f);   // RNE
    return *reinterpret_cast<u16*>(&b);
}
__device__ inline float bf2f(u16 u) {
    union { unsigned int i; float f; } c; c.i = ((unsigned int)u) << 16; return c.f;
}

__device__ inline void gload_lds16(const void* g, void* l) {
    __builtin_amdgcn_global_load_lds(
        (const __attribute__((address_space(1))) void*)g,
        (__attribute__((address_space(3))) void*)l, 16, 0, 0);
}

// ---------------------------------------------------------------------------
// split fp32 [R][1024] -> bf16 [R][2048]: cols 0:1024 = hi, 1024:2048 = lo
// ---------------------------------------------------------------------------
__global__ __launch_bounds__(256)
void split_hilo(const float* __restrict__ in, u16* __restrict__ outp, int n4) {
    int i = blockIdx.x * 256 + threadIdx.x;
    if (i >= n4) return;
    size_t e = (size_t)i * 4;
    size_t row = e >> 10; int col = (int)(e & 1023);
    float4 v = *(const float4*)&in[e];
    ushort4 hi, lo;
    hi.x = f2bf(v.x); lo.x = f2bf(v.x - bf2f(hi.x));
    hi.y = f2bf(v.y); lo.y = f2bf(v.y - bf2f(hi.y));
    hi.z = f2bf(v.z); lo.z = f2bf(v.z - bf2f(hi.z));
    hi.w = f2bf(v.w); lo.w = f2bf(v.w - bf2f(hi.w));
    size_t ob = row * 2048 + col;
    *(ushort4*)&outp[ob] = hi;
    *(ushort4*)&outp[ob + 1024] = lo;
}

// ---------------------------------------------------------------------------
// bf16-split NT GEMM, 256x256 tile, BK=64, 8 waves, 8-phase counted-vmcnt.
// A phys [M][2048] (hi|lo), W phys [1024][2048] (hi|lo). Logical K'=3072.
// A phys k-offset: k0<2048 ? k0 : k0-2048   ([hi, lo, hi])
// W phys k-offset: k0<1024 ? k0 : k0-1024   ([hi, hi, lo])
// LDS: 2 bufs x {A0[128x64], A1, B0[128x64], B1} bf16, XOR-swizzled chunks.
// Pipeline per K-tile t (4 phases):
//   ph1: ds_read 8 B-frags + A-quad0; stage A0(t+1) -> buf^1
//   ph2: ds_read A-quad1;            stage A1(t+1) -> buf^1
//   ph3: ds_read A-quad2;            stage B0(t+2) -> buf   (B read done ph1)
//   ph4: ds_read A-quad3;            stage B1(t+2) -> buf ; vmcnt(4)
// each phase: [reads; stage; barrier; lgkmcnt(0); setprio(1); 16 MFMA; setprio(0); barrier]
// vmcnt(4) at tile end leaves only B(t+2)'s 4 loads in flight -> A(t+1),B(t+1) landed.
// EPI: 0=q fp32 head relu+eps, 1=k bf16 head relu+eps, 2=v bf16 head, 3=fp32 rowmajor
// ---------------------------------------------------------------------------
template<int EPI>
__global__ __launch_bounds__(512, 2)
void gemm_split(const u16* __restrict__ A, const u16* __restrict__ Wsp,
                const float* __restrict__ bias, void* __restrict__ out) {
    __shared__ u16 lds[65536];   // 128 KiB: buf b at b*32768; A0:0 A1:8192 B0:16384 B1:24576

    // XCD-chunked swizzle: 512 blocks = 128 m-tiles x 4 n-tiles, 64 blocks/XCD
    int bid = blockIdx.x;
    int tl  = (bid & 7) * 64 + (bid >> 3);
    const int m0 = (tl >> 2) * 256;
    const int n0 = (tl & 3) * 256;

    const int tid = threadIdx.x;
    const int w = tid >> 6, l = tid & 63;
    const int wr = (w >> 2) * 128;          // wave M offset (0/128)
    const int wc = (w & 3) * 64;            // wave N offset (0..192)
    const int aReg = (w >> 2) * 8192;       // wave's A region offset in buf
    const int bReg = 16384 + ((w & 3) >> 1) * 8192;
    const int bLoc = ((w & 3) & 1) * 64;    // row offset within B region

    f32x4v acc[8][4];
    #pragma unroll
    for (int i = 0; i < 8; ++i)
        #pragma unroll
        for (int j = 0; j < 4; ++j) acc[i][j] = (f32x4v)0.f;

    // staging lane constants (XOR-swizzled source, linear LDS dest)
    const int srow = l >> 3;                     // 0..7 within 8-row chunk
    const int scol = ((l & 7) ^ srow) << 3;      // element offset 0..56

    const u16* Abase = A   + (size_t)m0 * 2048;
    const u16* Bbase = Wsp + (size_t)n0 * 2048;

    auto kaOf = [](int t) { int k0 = t * 64; return (k0 < 2048) ? k0 : k0 - 2048; };
    auto kwOf = [](int t) { int k0 = t * 64; return (k0 < 1024) ? k0 : k0 - 1024; };

    auto stageA = [&](int t, int half) {         // half-tile: rows 128*half..+127
        if (t >= 48) return;
        const u16* src = Abase + (size_t)(half * 128) * 2048 + kaOf(t) + scol;
        u16* dst = &lds[(t & 1) * 32768 + half * 8192];
        #pragma unroll
        for (int g = 0; g < 2; ++g) {
            int chunk = g * 8 + w;               // wave-uniform
            gload_lds16(src + (size_t)(chunk * 8 + srow) * 2048, dst + chunk * 512);
        }
    };
    auto stageB = [&](int t, int half) {
        if (t >= 48) return;
        const u16* src = Bbase + (size_t)(half * 128) * 2048 + kwOf(t) + scol;
        u16* dst = &lds[(t & 1) * 32768 + 16384 + half * 8192];
        #pragma unroll
        for (int g = 0; g < 2; ++g) {
            int chunk = g * 8 + w;
            gload_lds16(src + (size_t)(chunk * 8 + srow) * 2048, dst + chunk * 512);
        }
    };

    // prologue: tile0 fully + tile1's B; leaves B(1) (4 loads) outstanding at vmcnt(4)
    stageA(0, 0); stageA(0, 1); stageB(0, 0); stageB(0, 1);
    stageB(1, 0); stageB(1, 1);
    asm volatile("s_waitcnt vmcnt(4)" ::: "memory");
    __builtin_amdgcn_s_barrier();

    for (int t = 0; t < 48; ++t) {
        __builtin_amdgcn_sched_barrier(0);
        const char* aRg = (const char*)&lds[(t & 1) * 32768 + aReg];
        const char* bRg = (const char*)&lds[(t & 1) * 32768 + bReg];
        const int cb = (l >> 4) << 4;            // lane col-byte within K-group

        bf16x8v bF[4][2], aF[2][2];
        // ---------------- phase 1: all B-frags + A-quad0 ----------------
        #pragma unroll
        for (int fn = 0; fn < 4; ++fn)
            #pragma unroll
            for (int ks = 0; ks < 2; ++ks) {
                int r = bLoc + fn * 16 + (l & 15);
                bF[fn][ks] = *(const bf16x8v*)(bRg + r * 128 + ((ks * 64 + cb) ^ ((r & 7) << 4)));
            }
        #pragma unroll
        for (int f = 0; f < 2; ++f)
            #pragma unroll
            for (int ks = 0; ks < 2; ++ks) {
                int r = f * 16 + (l & 15);
                aF[f][ks] = *(const bf16x8v*)(aRg + r * 128 + ((ks * 64 + cb) ^ ((r & 7) << 4)));
            }
        stageA(t + 1, 0);
        __builtin_amdgcn_s_barrier();
        asm volatile("s_waitcnt lgkmcnt(0)" ::: "memory");
        __builtin_amdgcn_s_setprio(1);
        #pragma unroll
        for (int f = 0; f < 2; ++f)
            #pragma unroll
            for (int fn = 0; fn < 4; ++fn)
                #pragma unroll
                for (int ks = 0; ks < 2; ++ks)
                    acc[f][fn] = __builtin_amdgcn_mfma_f32_16x16x32_bf16(
                        aF[f][ks], bF[fn][ks], acc[f][fn], 0, 0, 0);
        __builtin_amdgcn_s_setprio(0);
        __builtin_amdgcn_s_barrier();

        // ---------------- phases 2..4: A-quad q ----------------
        #pragma unroll
        for (int q = 1; q < 4; ++q) {
            #pragma unroll
            for (int f = 0; f < 2; ++f)
                #pragma unroll
                for (int ks = 0; ks < 2; ++ks) {
                    int r = q * 32 + f * 16 + (l & 15);
                    aF[f][ks] = *(const bf16x8v*)(aRg + r * 128 + ((ks * 64 + cb) ^ ((r & 7) << 4)));
                }
            if (q == 1)      stageA(t + 1, 1);
            else if (q == 2) stageB(t + 2, 0);
            else             stageB(t + 2, 1);
            __builtin_amdgcn_s_barrier();
            asm volatile("s_waitcnt lgkmcnt(0)" ::: "memory");
            __builtin_amdgcn_s_setprio(1);
            #pragma unroll
            for (int f = 0; f < 2; ++f)
                #pragma unroll
                for (int fn = 0; fn < 4; ++fn)
                    #pragma unroll
                    for (int ks = 0; ks < 2; ++ks)
                        acc[q * 2 + f][fn] = __builtin_amdgcn_mfma_f32_16x16x32_bf16(
                            aF[f][ks], bF[fn][ks], acc[q * 2 + f][fn], 0, 0, 0);
            __builtin_amdgcn_s_setprio(0);
            if (q == 3) asm volatile("s_waitcnt vmcnt(4)" ::: "memory");
            __builtin_amdgcn_s_barrier();
        }
    }

    float bv4[4];
    #pragma unroll
    for (int fn = 0; fn < 4; ++fn) bv4[fn] = bias[n0 + wc + fn * 16 + (l & 15)];

    #pragma unroll
    for (int mf = 0; mf < 8; ++mf)
        #pragma unroll
        for (int fn = 0; fn < 4; ++fn)
            #pragma unroll
            for (int r = 0; r < 4; ++r) {
                int m = m0 + wr + mf * 16 + ((l >> 4) << 2) + r;
                int n = n0 + wc + fn * 16 + (l & 15);
                float o = acc[mf][fn][r] + bv4[fn];
                if (EPI == 0 || EPI == 1) o = fmaxf(o, 0.f) + EPSV;
                if (EPI <= 2) {
                    int b = m >> 13, s = m & (SS - 1), h = n >> 6, d = n & 63;
                    size_t idx = (((size_t)b * HH + h) * SS + s) * DKK + d;
                    if (EPI == 0) ((float*)out)[idx] = o;
                    else          ((u16*)out)[idx]   = f2bf(o);
                } else {
                    ((float*)out)[(size_t)m * DD + n] = o;
                }
            }
}

// ---------------------------------------------------------------------------
// kv[bh][d][e] = sum_s k[bh][s][d]*v[bh][s][e]; ksum[bh][d] = sum_s k[bh][s][d]
// ---------------------------------------------------------------------------
__global__ __launch_bounds__(256)
void kv_ksum_kernel(const u16* __restrict__ k, const u16* __restrict__ v,
                    float* __restrict__ kv, float* __restrict__ ksum) {
    __shared__ float kt[64][64];
    __shared__ float vt[64][64];
    const int bh = blockIdx.y;
    const int tid = threadIdx.x;
    const int d0 = (tid >> 4) << 2;
    const int e0 = (tid & 15) << 2;
    float acc[4][4];
    #pragma unroll
    for (int i = 0; i < 4; ++i)
        #pragma unroll
        for (int j = 0; j < 4; ++j) acc[i][j] = 0.f;
    float ksl = 0.f;

    const size_t base = ((size_t)bh * SS + (size_t)blockIdx.x * 512) * DKK;
    for (int sub = 0; sub < 8; ++sub) {
        #pragma unroll
        for (int it = 0; it < 4; ++it) {
            int f = tid + it * 256;
            int r = f >> 4, c = (f & 15) << 2;
            ushort4 ku = *(const ushort4*)&k[base + sub * 4096 + (size_t)r * 64 + c];
            ushort4 vu = *(const ushort4*)&v[base + sub * 4096 + (size_t)r * 64 + c];
            *(float4*)&kt[r][c] = make_float4(bf2f(ku.x), bf2f(ku.y), bf2f(ku.z), bf2f(ku.w));
            *(float4*)&vt[r][c] = make_float4(bf2f(vu.x), bf2f(vu.y), bf2f(vu.z), bf2f(vu.w));
        }
        __syncthreads();
        for (int ss = 0; ss < 64; ++ss) {
            float4 ka = *(const float4*)&kt[ss][d0];
            float4 va = *(const float4*)&vt[ss][e0];
            float ar[4] = {ka.x, ka.y, ka.z, ka.w};
            float vr[4] = {va.x, va.y, va.z, va.w};
            #pragma unroll
            for (int i = 0; i < 4; ++i)
                #pragma unroll
                for (int j = 0; j < 4; ++j)
                    acc[i][j] = fmaf(ar[i], vr[j], acc[i][j]);
        }
        if (tid < 64) {
            for (int ss = 0; ss < 64; ++ss) ksl += kt[ss][tid];
        }
        __syncthreads();
    }
    float* kvb = kv + (size_t)bh * 4096;
    #pragma unroll
    for (int i = 0; i < 4; ++i)
        #pragma unroll
        for (int j = 0; j < 4; ++j)
            atomicAdd(&kvb[(d0 + i) * 64 + (e0 + j)], acc[i][j]);
    if (tid < 64) atomicAdd(&ksum[bh * 64 + tid], ksl);
}

// ---------------------------------------------------------------------------
// mid[m][:] = (q·kv)/(q·ksum+EPS) written SPLIT bf16: [m][h*64+e] hi, +1024 lo
// ---------------------------------------------------------------------------
__global__ __launch_bounds__(256)
void qkv_norm_kernel(const float* __restrict__ q, const float* __restrict__ kv,
                     const float* __restrict__ ksum, u16* __restrict__ mid) {
    __shared__ float kvs[64][65];
    __shared__ float ks[64];
    __shared__ float qrow[4][64];
    const int bh = blockIdx.y, b = bh >> 4, h = bh & 15;
    const int tid = threadIdx.x;
    for (int i = tid; i < 4096; i += 256) kvs[i >> 6][i & 63] = kv[(size_t)bh * 4096 + i];
    if (tid < 64) ks[tid] = ksum[bh * 64 + tid];
    __syncthreads();
    const int g = tid >> 6, lane = tid & 63;
    float kvc[64];
    #pragma unroll
    for (int d = 0; d < 64; ++d) kvc[d] = kvs[d][lane];
    const float ksl = ks[lane];
    const size_t qbase = (size_t)bh * SS * DKK;
    const int s0 = blockIdx.x * 256;
    for (int it = 0; it < 64; ++it) {
        int s = s0 + (it << 2) + g;
        float qv = q[qbase + (size_t)s * DKK + lane];
        qrow[g][lane] = qv;
        float qks = qv * ksl;
        #pragma unroll
        for (int off = 32; off >= 1; off >>= 1) qks += __shfl_xor(qks, off, 64);
        float o = 0.f;
        #pragma unroll
        for (int d4 = 0; d4 < 64; d4 += 4) {
            float4 qq = *(const float4*)&qrow[g][d4];
            o = fmaf(qq.x, kvc[d4 + 0], o);
            o = fmaf(qq.y, kvc[d4 + 1], o);
            o = fmaf(qq.z, kvc[d4 + 2], o);
            o = fmaf(qq.w, kvc[d4 + 3], o);
        }
        o = o / (qks + EPSV);
        u16 hi = f2bf(o);
        u16 lo = f2bf(o - bf2f(hi));
        size_t ob = ((size_t)b * SS + s) * 2048 + h * DKK + lane;
        mid[ob] = hi;
        mid[ob + 1024] = lo;
    }
}

// ---------------------------------------------------------------------------
extern "C" void kernel_launch(void* const* d_in, const int* in_sizes, int n_in,
                              void* d_out, int out_size, void* d_ws, size_t ws_size,
                              hipStream_t stream) {
    const float* x  = (const float*)d_in[0];
    const float* Wq = (const float*)d_in[1];
    const float* bq = (const float*)d_in[2];
    const float* Wk = (const float*)d_in[3];
    const float* bk = (const float*)d_in[4];
    const float* Wv = (const float*)d_in[5];
    const float* bv = (const float*)d_in[6];
    const float* Wo = (const float*)d_in[7];
    const float* bo = (const float*)d_in[8];

    char* ws = (char*)d_ws;
    u16*   xsplit  = (u16*)ws;                          // 134,217,728 B
    u16*   wsplit  = (u16*)(ws + 134217728);            //   4,194,304 B
    u16*   k_ws    = (u16*)(ws + 138412032);            //  67,108,864 B
    u16*   v_ws    = (u16*)(ws + 205520896);            //  67,108,864 B
    float* kv_ws   = (float*)(ws + 272629760);          //   1,048,576 B
    float* ksum_ws = (float*)(ws + 273678336);          //      16,384 B
    u16*   midsplit = xsplit;                           // overlays xsplit (dead)
    float* q_ws    = (float*)d_out;                     // q in d_out (fp32 head)

    split_hilo<<<32768, 256, 0, stream>>>(x, xsplit, 8388608);

    split_hilo<<<1024, 256, 0, stream>>>(Wq, wsplit, 262144);
    gemm_split<0><<<512, 512, 0, stream>>>(xsplit, wsplit, bq, (void*)q_ws);
    split_hilo<<<1024, 256, 0, stream>>>(Wk, wsplit, 262144);
    gemm_split<1><<<512, 512, 0, stream>>>(xsplit, wsplit, bk, (void*)k_ws);
    split_hilo<<<1024, 256, 0, stream>>>(Wv, wsplit, 262144);
    gemm_split<2><<<512, 512, 0, stream>>>(xsplit, wsplit, bv, (void*)v_ws);

    hipMemsetAsync(kv_ws, 0, 1048576 + 16384, stream);
    kv_ksum_kernel<<<dim3(16, 64), 256, 0, stream>>>(k_ws, v_ws, kv_ws, ksum_ws);
    qkv_norm_kernel<<<dim3(32, 64), 256, 0, stream>>>(q_ws, kv_ws, ksum_ws, midsplit);

    split_hilo<<<1024, 256, 0, stream>>>(Wo, wsplit, 262144);
    gemm_split<3><<<512, 512, 0, stream>>>(midsplit, wsplit, bo, d_out);
}

// Round 4
// 1152.053 us; speedup vs baseline: 2.9727x; 1.0241x over previous
//
#include <hip/hip_runtime.h>
#include <hip/hip_bf16.h>

#define BB 4
#define SS 8192
#define DD 1024
#define HH 16
#define DKK 64
#define EPSV 1e-6f
// M_TOTAL = 32768, logical K' = 3072 (hi*hi | lo*hi | hi*lo), 48 K-tiles of 64

typedef unsigned short u16;
typedef __attribute__((ext_vector_type(8))) short bf16x8v;
typedef __attribute__((ext_vector_type(4))) float f32x4v;

__device__ inline u16 f2bf(float f) {
    __hip_bfloat16 b = __float2bfloat16(f);   // RNE
    return *reinterpret_cast<u16*>(&b);
}
__device__ inline float bf2f(u16 u) {
    union { unsigned int i; float f; } c; c.i = ((unsigned int)u) << 16; return c.f;
}

__device__ inline void gload_lds16(const void* g, void* l) {
    __builtin_amdgcn_global_load_lds(
        (const __attribute__((address_space(1))) void*)g,
        (__attribute__((address_space(3))) void*)l, 16, 0, 0);
}

// ---------------------------------------------------------------------------
// split fp32 [R][1024] -> bf16 [R][2048]: cols 0:1024 = hi, 1024:2048 = lo
// ---------------------------------------------------------------------------
__global__ __launch_bounds__(256)
void split_hilo(const float* __restrict__ in, u16* __restrict__ outp, int n4) {
    int i = blockIdx.x * 256 + threadIdx.x;
    if (i >= n4) return;
    size_t e = (size_t)i * 4;
    size_t row = e >> 10; int col = (int)(e & 1023);
    float4 v = *(const float4*)&in[e];
    ushort4 hi, lo;
    hi.x = f2bf(v.x); lo.x = f2bf(v.x - bf2f(hi.x));
    hi.y = f2bf(v.y); lo.y = f2bf(v.y - bf2f(hi.y));
    hi.z = f2bf(v.z); lo.z = f2bf(v.z - bf2f(hi.z));
    hi.w = f2bf(v.w); lo.w = f2bf(v.w - bf2f(hi.w));
    size_t ob = row * 2048 + col;
    *(ushort4*)&outp[ob] = hi;
    *(ushort4*)&outp[ob + 1024] = lo;
}

// ---------------------------------------------------------------------------
// bf16-split NT GEMM, 256x256 tile, BK=64, 8 waves, quadrant 8-phase schedule.
// EPI 0: q  -> fp32 head layout, relu+eps, + qks = q . ksum (shuffle reduce)
// EPI 1: kv -> k (relu+eps, bf16 head) for n<1024, v (bf16 head) for n>=1024
// EPI 3: o  -> fp32 row-major
// NT = number of 256-wide n-tiles (4 for N=1024, 8 for N=2048); grid 128*NT.
// ---------------------------------------------------------------------------
template<int EPI, int NT>
__global__ __launch_bounds__(512, 2)
void gemm_split(const u16* __restrict__ A, const u16* __restrict__ Wsp,
                const float* __restrict__ bias, const float* __restrict__ bias2,
                void* __restrict__ out, void* __restrict__ out2,
                const float* __restrict__ ksum, float* __restrict__ qks) {
    __shared__ u16 lds[65536];   // 128 KiB: buf b at b*32768; A0:0 A1:8192 B0:16384 B1:24576

    constexpr int CHUNK = 128 * NT / 8;      // blocks per XCD
    int bid = blockIdx.x;
    int tl  = (bid & 7) * CHUNK + (bid >> 3);
    const int m0 = (tl / NT) * 256;
    const int n0 = (tl % NT) * 256;

    const int tid = threadIdx.x;
    const int w = tid >> 6, l = tid & 63;
    const int wr = (w >> 2) * 128;          // wave M offset (0/128)
    const int wc = (w & 3) * 64;            // wave N offset (0..192)
    const int aReg = (w >> 2) * 8192;       // wave's A region offset in buf
    const int bReg = 16384 + ((w & 3) >> 1) * 8192;
    const int bLoc = ((w & 3) & 1) * 64;    // row offset within B region

    f32x4v acc[8][4];
    #pragma unroll
    for (int i = 0; i < 8; ++i)
        #pragma unroll
        for (int j = 0; j < 4; ++j) acc[i][j] = (f32x4v)0.f;

    const int srow = l >> 3;                     // 0..7 within 8-row chunk
    const int scol = ((l & 7) ^ srow) << 3;      // swizzled col, elements

    const u16* Abase = A   + (size_t)m0 * 2048;
    const u16* Bbase = Wsp + (size_t)n0 * 2048;

    auto kaOf = [](int t) { int k0 = t * 64; return (k0 < 2048) ? k0 : k0 - 2048; };
    auto kwOf = [](int t) { int k0 = t * 64; return (k0 < 1024) ? k0 : k0 - 1024; };

    auto stageA = [&](int t, int half) {
        if (t >= 48) return;
        const u16* src = Abase + (size_t)(half * 128) * 2048 + kaOf(t) + scol;
        u16* dst = &lds[(t & 1) * 32768 + half * 8192];
        #pragma unroll
        for (int g = 0; g < 2; ++g) {
            int chunk = g * 8 + w;
            gload_lds16(src + (size_t)(chunk * 8 + srow) * 2048, dst + chunk * 512);
        }
    };
    auto stageB = [&](int t, int half) {
        if (t >= 48) return;
        const u16* src = Bbase + (size_t)(half * 128) * 2048 + kwOf(t) + scol;
        u16* dst = &lds[(t & 1) * 32768 + 16384 + half * 8192];
        #pragma unroll
        for (int g = 0; g < 2; ++g) {
            int chunk = g * 8 + w;
            gload_lds16(src + (size_t)(chunk * 8 + srow) * 2048, dst + chunk * 512);
        }
    };

    // prologue: tile0 fully + tile1's B; vmcnt(4) leaves B(1) outstanding
    stageA(0, 0); stageA(0, 1); stageB(0, 0); stageB(0, 1);
    stageB(1, 0); stageB(1, 1);
    asm volatile("s_waitcnt vmcnt(4)" ::: "memory");
    __builtin_amdgcn_s_barrier();

    for (int t = 0; t < 48; ++t) {
        const char* aRg = (const char*)&lds[(t & 1) * 32768 + aReg];
        const char* bRg = (const char*)&lds[(t & 1) * 32768 + bReg];
        const int cb = (l >> 4) << 4;

        bf16x8v aF[4][2], bF0[2][2], bF1[2][2];
        // ---- p0: A-half0 (mf 0-3, 8 reads) + B-half0 (fn 0-1, 4 reads) ----
        #pragma unroll
        for (int f = 0; f < 4; ++f)
            #pragma unroll
            for (int ks = 0; ks < 2; ++ks) {
                int r = f * 16 + (l & 15);
                aF[f][ks] = *(const bf16x8v*)(aRg + r * 128 + ((ks * 64 + cb) ^ ((r & 7) << 4)));
            }
        #pragma unroll
        for (int f = 0; f < 2; ++f)
            #pragma unroll
            for (int ks = 0; ks < 2; ++ks) {
                int r = bLoc + f * 16 + (l & 15);
                bF0[f][ks] = *(const bf16x8v*)(bRg + r * 128 + ((ks * 64 + cb) ^ ((r & 7) << 4)));
            }
        stageA(t + 1, 0);
        __builtin_amdgcn_s_barrier();
        asm volatile("s_waitcnt lgkmcnt(0)" ::: "memory");
        __builtin_amdgcn_s_setprio(1);
        #pragma unroll
        for (int f = 0; f < 4; ++f)
            #pragma unroll
            for (int fn = 0; fn < 2; ++fn)
                #pragma unroll
                for (int ks = 0; ks < 2; ++ks)
                    acc[f][fn] = __builtin_amdgcn_mfma_f32_16x16x32_bf16(
                        aF[f][ks], bF0[fn][ks], acc[f][fn], 0, 0, 0);
        __builtin_amdgcn_s_setprio(0);
        __builtin_amdgcn_s_barrier();

        // ---- p1: B-half1 (fn 2-3, 4 reads) ----
        #pragma unroll
        for (int f = 0; f < 2; ++f)
            #pragma unroll
            for (int ks = 0; ks < 2; ++ks) {
                int r = bLoc + (2 + f) * 16 + (l & 15);
                bF1[f][ks] = *(const bf16x8v*)(bRg + r * 128 + ((ks * 64 + cb) ^ ((r & 7) << 4)));
            }
        stageA(t + 1, 1);
        __builtin_amdgcn_s_barrier();
        asm volatile("s_waitcnt lgkmcnt(0)" ::: "memory");
        __builtin_amdgcn_s_setprio(1);
        #pragma unroll
        for (int f = 0; f < 4; ++f)
            #pragma unroll
            for (int fn = 0; fn < 2; ++fn)
                #pragma unroll
                for (int ks = 0; ks < 2; ++ks)
                    acc[f][2 + fn] = __builtin_amdgcn_mfma_f32_16x16x32_bf16(
                        aF[f][ks], bF1[fn][ks], acc[f][2 + fn], 0, 0, 0);
        __builtin_amdgcn_s_setprio(0);
        __builtin_amdgcn_s_barrier();

        // ---- p2: A-half1 (mf 4-7, 8 reads) ----
        #pragma unroll
        for (int f = 0; f < 4; ++f)
            #pragma unroll
            for (int ks = 0; ks < 2; ++ks) {
                int r = (4 + f) * 16 + (l & 15);
                aF[f][ks] = *(const bf16x8v*)(aRg + r * 128 + ((ks * 64 + cb) ^ ((r & 7) << 4)));
            }
        stageB(t + 2, 0);
        __builtin_amdgcn_s_barrier();
        asm volatile("s_waitcnt lgkmcnt(0)" ::: "memory");
        __builtin_amdgcn_s_setprio(1);
        #pragma unroll
        for (int f = 0; f < 4; ++f)
            #pragma unroll
            for (int fn = 0; fn < 2; ++fn)
                #pragma unroll
                for (int ks = 0; ks < 2; ++ks)
                    acc[4 + f][fn] = __builtin_amdgcn_mfma_f32_16x16x32_bf16(
                        aF[f][ks], bF0[fn][ks], acc[4 + f][fn], 0, 0, 0);
        __builtin_amdgcn_s_setprio(0);
        __builtin_amdgcn_s_barrier();

        // ---- p3: no reads ----
        stageB(t + 2, 1);
        __builtin_amdgcn_s_barrier();
        __builtin_amdgcn_s_setprio(1);
        #pragma unroll
        for (int f = 0; f < 4; ++f)
            #pragma unroll
            for (int fn = 0; fn < 2; ++fn)
                #pragma unroll
                for (int ks = 0; ks < 2; ++ks)
                    acc[4 + f][2 + fn] = __builtin_amdgcn_mfma_f32_16x16x32_bf16(
                        aF[f][ks], bF1[fn][ks], acc[4 + f][2 + fn], 0, 0, 0);
        __builtin_amdgcn_s_setprio(0);
        asm volatile("s_waitcnt vmcnt(4)" ::: "memory");
        __builtin_amdgcn_s_barrier();
    }

    // ------------------------------ epilogue ------------------------------
    const int lane15 = l & 15, lg = l >> 4;

    if (EPI == 1) {
        const bool isK = (n0 + wc) < 1024;
        const int nb = (n0 + wc) - (isK ? 0 : 1024);
        const float* bp = isK ? bias : bias2;
        u16* outp = (u16*)(isK ? out : out2);
        const int h = nb >> 6;
        float bv4[4];
        #pragma unroll
        for (int fn = 0; fn < 4; ++fn) bv4[fn] = bp[nb + fn * 16 + lane15];
        #pragma unroll
        for (int mf = 0; mf < 8; ++mf)
            #pragma unroll
            for (int fn = 0; fn < 4; ++fn)
                #pragma unroll
                for (int r = 0; r < 4; ++r) {
                    int m = m0 + wr + mf * 16 + lg * 4 + r;
                    int b = m >> 13, s = m & (SS - 1);
                    float o = acc[mf][fn][r] + bv4[fn];
                    if (isK) o = fmaxf(o, 0.f) + EPSV;
                    outp[(((size_t)b * HH + h) * SS + s) * DKK + fn * 16 + lane15] = f2bf(o);
                }
    } else if (EPI == 0) {
        const int b = m0 >> 13, h = (n0 + wc) >> 6;
        const int bh = b * HH + h;
        float bv4[4], ksc[4];
        #pragma unroll
        for (int fn = 0; fn < 4; ++fn) {
            bv4[fn] = bias[n0 + wc + fn * 16 + lane15];
            ksc[fn] = ksum[(size_t)bh * 64 + fn * 16 + lane15];
        }
        float* qo = (float*)out;
        #pragma unroll
        for (int mf = 0; mf < 8; ++mf)
            #pragma unroll
            for (int r = 0; r < 4; ++r) {
                int m = m0 + wr + mf * 16 + lg * 4 + r;
                int s = m & (SS - 1);
                float part = 0.f;
                #pragma unroll
                for (int fn = 0; fn < 4; ++fn) {
                    float o = fmaxf(acc[mf][fn][r] + bv4[fn], 0.f) + EPSV;
                    qo[((size_t)bh * SS + s) * DKK + fn * 16 + lane15] = o;
                    part += o * ksc[fn];
                }
                #pragma unroll
                for (int msk = 1; msk < 16; msk <<= 1)
                    part += __shfl_xor(part, msk, 16);
                if (lane15 == 0) qks[(size_t)bh * SS + s] = part;
            }
    } else {
        float bv4[4];
        #pragma unroll
        for (int fn = 0; fn < 4; ++fn) bv4[fn] = bias[n0 + wc + fn * 16 + lane15];
        float* op = (float*)out;
        #pragma unroll
        for (int mf = 0; mf < 8; ++mf)
            #pragma unroll
            for (int fn = 0; fn < 4; ++fn)
                #pragma unroll
                for (int r = 0; r < 4; ++r) {
                    int m = m0 + wr + mf * 16 + lg * 4 + r;
                    op[(size_t)m * DD + n0 + wc + fn * 16 + lane15] = acc[mf][fn][r] + bv4[fn];
                }
    }
}

// ---------------------------------------------------------------------------
// kv[bh][d][e] = sum_s k*v ; ksum[bh][d] = sum_s k.  8x8 register tiles,
// bf16 LDS double-buffered via global_load_lds, 4 wave-sgroups over s,
// LDS cross-group reduce, atomics to global (memset'd).  grid (8, 64).
// ---------------------------------------------------------------------------
__global__ __launch_bounds__(256)
void kv_ksum2(const u16* __restrict__ k, const u16* __restrict__ v,
              float* __restrict__ kv, float* __restrict__ ksum) {
    __shared__ u16 kb[2][4096];     // 64x64 bf16 per buf
    __shared__ u16 vb[2][4096];
    __shared__ float red[8192];     // 32 KB reduce scratch
    const int bh = blockIdx.y;
    const int tid = threadIdx.x;
    const int w = tid >> 6, l = tid & 63;
    const int d0 = (l >> 3) * 8, e0 = (l & 7) * 8;
    const size_t base = ((size_t)bh * SS + (size_t)blockIdx.x * 1024) * DKK;

    float acc[8][8];
    #pragma unroll
    for (int i = 0; i < 8; ++i)
        #pragma unroll
        for (int j = 0; j < 8; ++j) acc[i][j] = 0.f;
    float ksl[8];
    #pragma unroll
    for (int i = 0; i < 8; ++i) ksl[i] = 0.f;

    auto stage = [&](int j, int buf) {
        const u16* ksrc = k + base + (size_t)j * 4096;
        const u16* vsrc = v + base + (size_t)j * 4096;
        #pragma unroll
        for (int g = 0; g < 2; ++g) {
            int c = g * 4 + w;                    // 8 chunks of 1 KB
            gload_lds16(ksrc + c * 512 + (size_t)l * 8, &kb[buf][c * 512]);
            gload_lds16(vsrc + c * 512 + (size_t)l * 8, &vb[buf][c * 512]);
        }
    };

    stage(0, 0);
    asm volatile("s_waitcnt vmcnt(0)" ::: "memory");
    __syncthreads();
    for (int j = 0; j < 16; ++j) {
        if (j < 15) stage(j + 1, (j + 1) & 1);
        const int buf = j & 1;
        #pragma unroll 4
        for (int i = 0; i < 16; ++i) {
            int ss = w * 16 + i;
            bf16x8v ku = *(const bf16x8v*)&kb[buf][ss * 64 + d0];
            bf16x8v vu = *(const bf16x8v*)&vb[buf][ss * 64 + e0];
            float ar[8], vr[8];
            #pragma unroll
            for (int q = 0; q < 8; ++q) { ar[q] = bf2f((u16)ku[q]); vr[q] = bf2f((u16)vu[q]); }
            #pragma unroll
            for (int q = 0; q < 8; ++q) ksl[q] += ar[q];
            #pragma unroll
            for (int ii = 0; ii < 8; ++ii)
                #pragma unroll
                for (int jj = 0; jj < 8; ++jj)
                    acc[ii][jj] = fmaf(ar[ii], vr[jj], acc[ii][jj]);
        }
        asm volatile("s_waitcnt vmcnt(0)" ::: "memory");
        __syncthreads();
    }

    // cross-sgroup reduce (2 halves of d-range), then atomics
    #pragma unroll
    for (int half = 0; half < 2; ++half) {
        __syncthreads();
        if ((d0 >> 5) == half) {
            #pragma unroll
            for (int ii = 0; ii < 8; ++ii) {
                #pragma unroll
                for (int j4 = 0; j4 < 2; ++j4)
                    *(float4*)&red[w * 2048 + ((d0 & 31) + ii) * 64 + e0 + j4 * 4] =
                        *(float4*)&acc[ii][j4 * 4];
            }
        }
        __syncthreads();
        float* kvb = kv + (size_t)bh * 4096 + half * 2048;
        #pragma unroll
        for (int u = 0; u < 8; ++u) {
            int o = u * 256 + tid;
            float s4 = red[o] + red[2048 + o] + red[4096 + o] + red[6144 + o];
            atomicAdd(&kvb[o], s4);
        }
    }
    __syncthreads();
    if (e0 == 0) {
        #pragma unroll
        for (int ii = 0; ii < 8; ++ii) red[w * 64 + d0 + ii] = ksl[ii];
    }
    __syncthreads();
    if (tid < 64)
        atomicAdd(&ksum[(size_t)bh * 64 + tid],
                  red[tid] + red[64 + tid] + red[128 + tid] + red[192 + tid]);
}

// ---------------------------------------------------------------------------
// mid[m][:] = (q.kv)/(qks+EPS), written SPLIT bf16: [m][h*64+e] hi, +1024 lo
// ---------------------------------------------------------------------------
__global__ __launch_bounds__(256)
void qkv_norm2(const float* __restrict__ q, const float* __restrict__ kvm,
               const float* __restrict__ qks, u16* __restrict__ mid) {
    __shared__ float kvs[64][65];
    __shared__ float qrow[4][64];
    const int bh = blockIdx.y, b = bh >> 4, h = bh & 15;
    const int tid = threadIdx.x;
    for (int i = tid; i < 4096; i += 256) kvs[i >> 6][i & 63] = kvm[(size_t)bh * 4096 + i];
    __syncthreads();
    const int g = tid >> 6, lane = tid & 63;
    float kvc[64];
    #pragma unroll
    for (int d = 0; d < 64; ++d) kvc[d] = kvs[d][lane];
    const size_t qbase = (size_t)bh * SS * DKK;
    const int s0 = blockIdx.x * 256;
    for (int it = 0; it < 64; ++it) {
        int s = s0 + (it << 2) + g;
        float qv = q[qbase + (size_t)s * DKK + lane];
        qrow[g][lane] = qv;
        float den = qks[(size_t)bh * SS + s] + EPSV;
        float o = 0.f;
        #pragma unroll
        for (int d4 = 0; d4 < 64; d4 += 4) {
            float4 qq = *(const float4*)&qrow[g][d4];
            o = fmaf(qq.x, kvc[d4 + 0], o);
            o = fmaf(qq.y, kvc[d4 + 1], o);
            o = fmaf(qq.z, kvc[d4 + 2], o);
            o = fmaf(qq.w, kvc[d4 + 3], o);
        }
        o = o / den;
        u16 hi = f2bf(o);
        u16 lo = f2bf(o - bf2f(hi));
        size_t ob = ((size_t)b * SS + s) * 2048 + h * DKK + lane;
        mid[ob] = hi;
        mid[ob + 1024] = lo;
    }
}

// ---------------------------------------------------------------------------
extern "C" void kernel_launch(void* const* d_in, const int* in_sizes, int n_in,
                              void* d_out, int out_size, void* d_ws, size_t ws_size,
                              hipStream_t stream) {
    const float* x  = (const float*)d_in[0];
    const float* Wq = (const float*)d_in[1];
    const float* bq = (const float*)d_in[2];
    const float* Wk = (const float*)d_in[3];
    const float* bk = (const float*)d_in[4];
    const float* Wv = (const float*)d_in[5];
    const float* bv = (const float*)d_in[6];
    const float* Wo = (const float*)d_in[7];
    const float* bo = (const float*)d_in[8];

    char* ws = (char*)d_ws;
    u16*   xsplit  = (u16*)ws;                          // 134,217,728 B
    u16*   wsp     = (u16*)(ws + 134217728);            //   8,388,608 B (2048x2048)
    float* qks_ws  = (float*)(ws + 134217728 + 4194304);// overlays wsp upper 4MB when wsp holds only 1024 rows
    u16*   k_ws    = (u16*)(ws + 142606336);            //  67,108,864 B
    u16*   v_ws    = (u16*)(ws + 209715200);            //  67,108,864 B
    float* kv_ws   = (float*)(ws + 276824064);          //   1,048,576 B
    float* ksum_ws = (float*)(ws + 277872640);          //      16,384 B
    u16*   midsplit = xsplit;                           // overlays xsplit (dead)
    float* q_ws    = (float*)d_out;                     // q in d_out (fp32 head)

    split_hilo<<<32768, 256, 0, stream>>>(x, xsplit, 8388608);
    split_hilo<<<1024, 256, 0, stream>>>(Wk, wsp, 262144);
    split_hilo<<<1024, 256, 0, stream>>>(Wv, wsp + (size_t)1024 * 2048, 262144);
    hipMemsetAsync(kv_ws, 0, 1048576 + 16384, stream);

    gemm_split<1, 8><<<1024, 512, 0, stream>>>(xsplit, wsp, bk, bv,
                                               (void*)k_ws, (void*)v_ws, nullptr, nullptr);
    kv_ksum2<<<dim3(8, 64), 256, 0, stream>>>(k_ws, v_ws, kv_ws, ksum_ws);

    split_hilo<<<1024, 256, 0, stream>>>(Wq, wsp, 262144);
    gemm_split<0, 4><<<512, 512, 0, stream>>>(xsplit, wsp, bq, nullptr,
                                              (void*)q_ws, nullptr, ksum_ws, qks_ws);
    qkv_norm2<<<dim3(32, 64), 256, 0, stream>>>(q_ws, kv_ws, qks_ws, midsplit);

    split_hilo<<<1024, 256, 0, stream>>>(Wo, wsp, 262144);
    gemm_split<3, 4><<<512, 512, 0, stream>>>(midsplit, wsp, bo, nullptr,
                                              d_out, nullptr, nullptr, nullptr);
}